// Round 1
// baseline (6011.169 us; speedup 1.0000x reference)
//
#include <hip/hip_runtime.h>
#include <hip/hip_bf16.h>

// Problem constants (from reference): B=4, S=2048, D=1024, H=16, HD=64
constexpr int B = 4, S = 2048, D = 1024, H = 16, HD = 64;
constexpr int M = B * S;  // 8192 rows of x

// ---------------------------------------------------------------------------
// Kernel 1: fused QKV projection. q/k/v = x @ W^T + b, written directly into
// [B,H,S,HD] layout in workspace. Classic 128x128x16 fp32 tile, 8x8 microtile.
// NT GEMM: both x rows and W rows are contiguous in K.
// ---------------------------------------------------------------------------
constexpr int TM = 128, TN = 128, TK = 16;

__global__ __launch_bounds__(256) void qkv_proj_kernel(
    const float* __restrict__ x,
    const float* __restrict__ Wq, const float* __restrict__ bq,
    const float* __restrict__ Wk, const float* __restrict__ bk,
    const float* __restrict__ Wv, const float* __restrict__ bv,
    float* __restrict__ ws)
{
    const int zi = blockIdx.z;
    const float* __restrict__ W    = (zi == 0) ? Wq : (zi == 1) ? Wk : Wv;
    const float* __restrict__ bias = (zi == 0) ? bq : (zi == 1) ? bk : bv;
    float* __restrict__ dst = ws + (size_t)zi * (size_t)M * D;

    const int m0 = blockIdx.x * TM;
    const int n0 = blockIdx.y * TN;
    const int tid = threadIdx.x;
    const int tx = tid & 15, ty = tid >> 4;

    // Transposed tiles [K][M] so the hot loop does ds_read_b128 along M/N.
    // Pad +4 keeps rows 16B-aligned (132 floats = 528B, divisible by 16).
    __shared__ float As[TK][TM + 4];
    __shared__ float Bs[TK][TN + 4];

    float acc[8][8];
    #pragma unroll
    for (int i = 0; i < 8; ++i)
        #pragma unroll
        for (int j = 0; j < 8; ++j) acc[i][j] = 0.f;

    for (int k0 = 0; k0 < D; k0 += TK) {
        #pragma unroll
        for (int l = 0; l < 2; ++l) {
            int fl = tid + l * 256;          // float4 slot 0..511
            int mm = fl >> 2;                // 0..127
            int k4 = (fl & 3) * 4;           // 0,4,8,12
            float4 a = *(const float4*)(x + (size_t)(m0 + mm) * D + k0 + k4);
            As[k4 + 0][mm] = a.x; As[k4 + 1][mm] = a.y;
            As[k4 + 2][mm] = a.z; As[k4 + 3][mm] = a.w;
            float4 w = *(const float4*)(W + (size_t)(n0 + mm) * D + k0 + k4);
            Bs[k4 + 0][mm] = w.x; Bs[k4 + 1][mm] = w.y;
            Bs[k4 + 2][mm] = w.z; Bs[k4 + 3][mm] = w.w;
        }
        __syncthreads();
        #pragma unroll
        for (int kk = 0; kk < TK; ++kk) {
            float a[8], bb[8];
            *(float4*)(a)      = *(const float4*)(&As[kk][ty * 8]);
            *(float4*)(a + 4)  = *(const float4*)(&As[kk][ty * 8 + 4]);
            *(float4*)(bb)     = *(const float4*)(&Bs[kk][tx * 8]);
            *(float4*)(bb + 4) = *(const float4*)(&Bs[kk][tx * 8 + 4]);
            #pragma unroll
            for (int i = 0; i < 8; ++i)
                #pragma unroll
                for (int j = 0; j < 8; ++j)
                    acc[i][j] += a[i] * bb[j];
        }
        __syncthreads();
    }

    // Epilogue: add bias, scatter to [B,H,S,HD]. TM=128 never crosses the
    // S=2048 batch boundary; TN=128 spans exactly 2 heads, each float4 stays
    // inside one head.
    #pragma unroll
    for (int i = 0; i < 8; ++i) {
        int mrow = m0 + ty * 8 + i;
        int b = mrow >> 11;          // / 2048
        int s = mrow & 2047;
        #pragma unroll
        for (int jj = 0; jj < 2; ++jj) {
            int n = n0 + tx * 8 + jj * 4;
            int h = n >> 6, hd = n & 63;
            float4 o;
            o.x = acc[i][jj * 4 + 0] + bias[n + 0];
            o.y = acc[i][jj * 4 + 1] + bias[n + 1];
            o.z = acc[i][jj * 4 + 2] + bias[n + 2];
            o.w = acc[i][jj * 4 + 3] + bias[n + 3];
            *(float4*)(dst + (((size_t)(b * H + h) * S + s) * HD + hd)) = o;
        }
    }
}

// ---------------------------------------------------------------------------
// Kernel 2: scores = q @ k^T (no scaling, per reference) + row softmax, fused.
// One WG = 8 query rows of one (b,h). Each thread owns 8 score columns
// (c = tid + j*256), all 8 rows -> 64 register-resident scores. q staged in
// LDS (broadcast reads). Row max/sum via shfl_xor + tiny LDS cross-wave step.
// Writes normalized probs exactly once, coalesced.
// ---------------------------------------------------------------------------
constexpr int MQ = 8;

__global__ __launch_bounds__(256) void scores_softmax_kernel(
    const float* __restrict__ qg, const float* __restrict__ kg,
    float* __restrict__ probs)
{
    const int b = blockIdx.z, h = blockIdx.y, qb = blockIdx.x;
    const int tid = threadIdx.x;
    const int s0 = qb * MQ;
    const float* __restrict__ qbase = qg + ((size_t)(b * H + h) * S + s0) * HD;
    const float* __restrict__ kbase = kg + (size_t)(b * H + h) * S * HD;
    float* __restrict__ pbase = probs + ((size_t)(b * H + h) * S + s0) * (size_t)S;

    __shared__ float qs[MQ][HD];
    __shared__ float red[MQ][4];

    if (tid < 128) {
        int r = tid >> 4, c4 = (tid & 15) * 4;
        *(float4*)(&qs[r][c4]) = *(const float4*)(qbase + r * HD + c4);
    }
    __syncthreads();

    float sc[MQ][8];
    #pragma unroll
    for (int r = 0; r < MQ; ++r)
        #pragma unroll
        for (int j = 0; j < 8; ++j) sc[r][j] = 0.f;

    #pragma unroll 2
    for (int kk4 = 0; kk4 < 16; ++kk4) {
        float4 qv[MQ];
        #pragma unroll
        for (int r = 0; r < MQ; ++r)
            qv[r] = *(const float4*)(&qs[r][kk4 * 4]);   // LDS broadcast (free)
        #pragma unroll
        for (int j = 0; j < 8; ++j) {
            int c = tid + j * 256;
            float4 kv = *(const float4*)(kbase + (size_t)c * HD + kk4 * 4);
            #pragma unroll
            for (int r = 0; r < MQ; ++r)
                sc[r][j] += qv[r].x * kv.x + qv[r].y * kv.y +
                            qv[r].z * kv.z + qv[r].w * kv.w;
        }
    }

    const int lane = tid & 63, wid = tid >> 6;

    // row max
    float rm[MQ];
    #pragma unroll
    for (int r = 0; r < MQ; ++r) {
        float mx = sc[r][0];
        #pragma unroll
        for (int j = 1; j < 8; ++j) mx = fmaxf(mx, sc[r][j]);
        #pragma unroll
        for (int off = 32; off > 0; off >>= 1)
            mx = fmaxf(mx, __shfl_xor(mx, off, 64));
        if (lane == 0) red[r][wid] = mx;
    }
    __syncthreads();
    #pragma unroll
    for (int r = 0; r < MQ; ++r)
        rm[r] = fmaxf(fmaxf(red[r][0], red[r][1]), fmaxf(red[r][2], red[r][3]));
    __syncthreads();  // red reused below

    // exp + row sum
    float inv[MQ];
    #pragma unroll
    for (int r = 0; r < MQ; ++r) {
        float sum = 0.f;
        #pragma unroll
        for (int j = 0; j < 8; ++j) {
            float e = __expf(sc[r][j] - rm[r]);
            sc[r][j] = e;
            sum += e;
        }
        #pragma unroll
        for (int off = 32; off > 0; off >>= 1)
            sum += __shfl_xor(sum, off, 64);
        if (lane == 0) red[r][wid] = sum;
    }
    __syncthreads();
    #pragma unroll
    for (int r = 0; r < MQ; ++r)
        inv[r] = 1.f / (red[r][0] + red[r][1] + red[r][2] + red[r][3]);

    // coalesced probs write (threads consecutive -> floats consecutive)
    #pragma unroll
    for (int r = 0; r < MQ; ++r)
        #pragma unroll
        for (int j = 0; j < 8; ++j)
            pbase[(size_t)r * S + tid + j * 256] = sc[r][j] * inv[r];
}

// ---------------------------------------------------------------------------
// Kernel 3: ctx = probs @ v -> out[B,S,D]. One WG = 8 query rows of one (b,h).
// hd = lane (coalesced v reads); probs reads are wave-uniform float4
// broadcasts. v block (512KB per (b,h)) is L2/L3-resident across the 256
// q-blocks that share it.
// ---------------------------------------------------------------------------
__global__ __launch_bounds__(256) void pv_kernel(
    const float* __restrict__ probs, const float* __restrict__ vg,
    float* __restrict__ out)
{
    const int b = blockIdx.z, h = blockIdx.y, qb = blockIdx.x;
    const int tid = threadIdx.x;
    const int hd = tid & 63, wid = tid >> 6;
    const int s0 = qb * 8;
    const float* __restrict__ vbase = vg + (size_t)(b * H + h) * S * HD;
    const float* __restrict__ pbase = probs + ((size_t)(b * H + h) * S + s0) * (size_t)S;
    const int r0 = wid, r1 = wid + 4;

    float acc0 = 0.f, acc1 = 0.f;
    #pragma unroll 4
    for (int c = 0; c < S; c += 4) {
        float4 p0 = *(const float4*)(pbase + (size_t)r0 * S + c);
        float4 p1 = *(const float4*)(pbase + (size_t)r1 * S + c);
        float v0 = vbase[(c + 0) * HD + hd];
        float v1 = vbase[(c + 1) * HD + hd];
        float v2 = vbase[(c + 2) * HD + hd];
        float v3 = vbase[(c + 3) * HD + hd];
        acc0 += p0.x * v0 + p0.y * v1 + p0.z * v2 + p0.w * v3;
        acc1 += p1.x * v0 + p1.y * v1 + p1.z * v2 + p1.w * v3;
    }
    out[((size_t)b * S + (s0 + r0)) * D + h * HD + hd] = acc0;
    out[((size_t)b * S + (s0 + r1)) * D + h * HD + hd] = acc1;
}

// ---------------------------------------------------------------------------
extern "C" void kernel_launch(void* const* d_in, const int* in_sizes, int n_in,
                              void* d_out, int out_size, void* d_ws, size_t ws_size,
                              hipStream_t stream)
{
    const float* x  = (const float*)d_in[0];
    const float* Wq = (const float*)d_in[1];
    const float* bq = (const float*)d_in[2];
    const float* Wk = (const float*)d_in[3];
    const float* bk = (const float*)d_in[4];
    const float* Wv = (const float*)d_in[5];
    const float* bv = (const float*)d_in[6];

    float* out   = (float*)d_out;                         // [B,S,D] first
    float* probs = out + (size_t)B * S * D;               // then [B,H,S,S]
    float* ws    = (float*)d_ws;                          // q,k,v scratch
    // Requires 3*M*D*4 = 100,663,296 bytes of workspace (q,k,v in [B,H,S,HD]).
    (void)ws_size;

    dim3 g1(M / TM, D / TN, 3);
    qkv_proj_kernel<<<g1, 256, 0, stream>>>(x, Wq, bq, Wk, bk, Wv, bv, ws);

    const float* q = ws;
    const float* k = ws + (size_t)M * D;
    const float* v = ws + 2 * (size_t)M * D;

    dim3 g2(S / MQ, H, B);
    scores_softmax_kernel<<<g2, 256, 0, stream>>>(q, k, probs);

    dim3 g3(S / 8, H, B);
    pv_kernel<<<g3, 256, 0, stream>>>(probs, v, out);
}

// Round 2
// 3378.539 us; speedup vs baseline: 1.7792x; 1.7792x over previous
//
#include <hip/hip_runtime.h>
#include <hip/hip_bf16.h>

// Problem constants (from reference): B=4, S=2048, D=1024, H=16, HD=64
constexpr int B = 4, S = 2048, D = 1024, H = 16, HD = 64;
constexpr int M = B * S;  // 8192 rows of x

// ---------------------------------------------------------------------------
// Kernel 1: fused QKV projection. q/k/v = x @ W^T + b, written directly into
// [B,H,S,HD] layout in workspace. Classic 128x128x16 fp32 tile, 8x8 microtile.
// ---------------------------------------------------------------------------
constexpr int TM = 128, TN = 128, TK = 16;

__global__ __launch_bounds__(256) void qkv_proj_kernel(
    const float* __restrict__ x,
    const float* __restrict__ Wq, const float* __restrict__ bq,
    const float* __restrict__ Wk, const float* __restrict__ bk,
    const float* __restrict__ Wv, const float* __restrict__ bv,
    float* __restrict__ ws)
{
    const int zi = blockIdx.z;
    const float* __restrict__ W    = (zi == 0) ? Wq : (zi == 1) ? Wk : Wv;
    const float* __restrict__ bias = (zi == 0) ? bq : (zi == 1) ? bk : bv;
    float* __restrict__ dst = ws + (size_t)zi * (size_t)M * D;

    const int m0 = blockIdx.x * TM;
    const int n0 = blockIdx.y * TN;
    const int tid = threadIdx.x;
    const int tx = tid & 15, ty = tid >> 4;

    __shared__ float As[TK][TM + 4];
    __shared__ float Bs[TK][TN + 4];

    float acc[8][8];
    #pragma unroll
    for (int i = 0; i < 8; ++i)
        #pragma unroll
        for (int j = 0; j < 8; ++j) acc[i][j] = 0.f;

    for (int k0 = 0; k0 < D; k0 += TK) {
        #pragma unroll
        for (int l = 0; l < 2; ++l) {
            int fl = tid + l * 256;          // float4 slot 0..511
            int mm = fl >> 2;                // 0..127
            int k4 = (fl & 3) * 4;           // 0,4,8,12
            float4 a = *(const float4*)(x + (size_t)(m0 + mm) * D + k0 + k4);
            As[k4 + 0][mm] = a.x; As[k4 + 1][mm] = a.y;
            As[k4 + 2][mm] = a.z; As[k4 + 3][mm] = a.w;
            float4 w = *(const float4*)(W + (size_t)(n0 + mm) * D + k0 + k4);
            Bs[k4 + 0][mm] = w.x; Bs[k4 + 1][mm] = w.y;
            Bs[k4 + 2][mm] = w.z; Bs[k4 + 3][mm] = w.w;
        }
        __syncthreads();
        #pragma unroll
        for (int kk = 0; kk < TK; ++kk) {
            float a[8], bb[8];
            *(float4*)(a)      = *(const float4*)(&As[kk][ty * 8]);
            *(float4*)(a + 4)  = *(const float4*)(&As[kk][ty * 8 + 4]);
            *(float4*)(bb)     = *(const float4*)(&Bs[kk][tx * 8]);
            *(float4*)(bb + 4) = *(const float4*)(&Bs[kk][tx * 8 + 4]);
            #pragma unroll
            for (int i = 0; i < 8; ++i)
                #pragma unroll
                for (int j = 0; j < 8; ++j)
                    acc[i][j] += a[i] * bb[j];
        }
        __syncthreads();
    }

    #pragma unroll
    for (int i = 0; i < 8; ++i) {
        int mrow = m0 + ty * 8 + i;
        int b = mrow >> 11;          // / 2048
        int s = mrow & 2047;
        #pragma unroll
        for (int jj = 0; jj < 2; ++jj) {
            int n = n0 + tx * 8 + jj * 4;
            int h = n >> 6, hd = n & 63;
            float4 o;
            o.x = acc[i][jj * 4 + 0] + bias[n + 0];
            o.y = acc[i][jj * 4 + 1] + bias[n + 1];
            o.z = acc[i][jj * 4 + 2] + bias[n + 2];
            o.w = acc[i][jj * 4 + 3] + bias[n + 3];
            *(float4*)(dst + (((size_t)(b * H + h) * S + s) * HD + hd)) = o;
        }
    }
}

// ---------------------------------------------------------------------------
// Kernel 2: scores = q @ k^T (no scaling, per reference) + row softmax, fused.
// One WG = 8 query rows of one (b,h). Unchanged from R1 (measure first).
// ---------------------------------------------------------------------------
constexpr int MQ = 8;

__global__ __launch_bounds__(256) void scores_softmax_kernel(
    const float* __restrict__ qg, const float* __restrict__ kg,
    float* __restrict__ probs)
{
    const int b = blockIdx.z, h = blockIdx.y, qb = blockIdx.x;
    const int tid = threadIdx.x;
    const int s0 = qb * MQ;
    const float* __restrict__ qbase = qg + ((size_t)(b * H + h) * S + s0) * HD;
    const float* __restrict__ kbase = kg + (size_t)(b * H + h) * S * HD;
    float* __restrict__ pbase = probs + ((size_t)(b * H + h) * S + s0) * (size_t)S;

    __shared__ float qs[MQ][HD];
    __shared__ float red[MQ][4];

    if (tid < 128) {
        int r = tid >> 4, c4 = (tid & 15) * 4;
        *(float4*)(&qs[r][c4]) = *(const float4*)(qbase + r * HD + c4);
    }
    __syncthreads();

    float sc[MQ][8];
    #pragma unroll
    for (int r = 0; r < MQ; ++r)
        #pragma unroll
        for (int j = 0; j < 8; ++j) sc[r][j] = 0.f;

    #pragma unroll 2
    for (int kk4 = 0; kk4 < 16; ++kk4) {
        float4 qv[MQ];
        #pragma unroll
        for (int r = 0; r < MQ; ++r)
            qv[r] = *(const float4*)(&qs[r][kk4 * 4]);   // LDS broadcast
        #pragma unroll
        for (int j = 0; j < 8; ++j) {
            int c = tid + j * 256;
            float4 kv = *(const float4*)(kbase + (size_t)c * HD + kk4 * 4);
            #pragma unroll
            for (int r = 0; r < MQ; ++r)
                sc[r][j] += qv[r].x * kv.x + qv[r].y * kv.y +
                            qv[r].z * kv.z + qv[r].w * kv.w;
        }
    }

    const int lane = tid & 63, wid = tid >> 6;

    float rm[MQ];
    #pragma unroll
    for (int r = 0; r < MQ; ++r) {
        float mx = sc[r][0];
        #pragma unroll
        for (int j = 1; j < 8; ++j) mx = fmaxf(mx, sc[r][j]);
        #pragma unroll
        for (int off = 32; off > 0; off >>= 1)
            mx = fmaxf(mx, __shfl_xor(mx, off, 64));
        if (lane == 0) red[r][wid] = mx;
    }
    __syncthreads();
    #pragma unroll
    for (int r = 0; r < MQ; ++r)
        rm[r] = fmaxf(fmaxf(red[r][0], red[r][1]), fmaxf(red[r][2], red[r][3]));
    __syncthreads();

    float inv[MQ];
    #pragma unroll
    for (int r = 0; r < MQ; ++r) {
        float sum = 0.f;
        #pragma unroll
        for (int j = 0; j < 8; ++j) {
            float e = __expf(sc[r][j] - rm[r]);
            sc[r][j] = e;
            sum += e;
        }
        #pragma unroll
        for (int off = 32; off > 0; off >>= 1)
            sum += __shfl_xor(sum, off, 64);
        if (lane == 0) red[r][wid] = sum;
    }
    __syncthreads();
    #pragma unroll
    for (int r = 0; r < MQ; ++r)
        inv[r] = 1.f / (red[r][0] + red[r][1] + red[r][2] + red[r][3]);

    #pragma unroll
    for (int r = 0; r < MQ; ++r)
        #pragma unroll
        for (int j = 0; j < 8; ++j)
            pbase[(size_t)r * S + tid + j * 256] = sc[r][j] * inv[r];
}

// ---------------------------------------------------------------------------
// Kernel 3 (REWRITTEN): ctx = probs @ v as a proper tiled GEMM.
// Per (b,h): out[2048x64] = P[2048x2048] @ V[2048x64].
// Tile 128x64, K-chunk 32, 256 threads, 8x4 microtile.
// R1 version was latency-bound (VALUBusy 22%, wave-uniform probs loads).
// ---------------------------------------------------------------------------
constexpr int PTM = 128, PTN = 64, PTK = 32;

__global__ __launch_bounds__(256) void pv_kernel(
    const float* __restrict__ probs, const float* __restrict__ vg,
    float* __restrict__ out)
{
    const int bh = blockIdx.y;                 // 0..63
    const int b = bh >> 4, h = bh & 15;
    const int m0 = blockIdx.x * PTM;
    const int tid = threadIdx.x;
    const int tx = tid & 15, ty = tid >> 4;

    const float* __restrict__ pbase = probs + ((size_t)bh * S + m0) * (size_t)S;
    const float* __restrict__ vbase = vg + (size_t)bh * S * HD;

    // Transposed P tile [K][M]; V tile [K][N]. Pads keep 16B alignment
    // (132 floats = 528B, 68 floats = 272B, both /16).
    __shared__ float As[PTK][PTM + 4];
    __shared__ float Bs[PTK][PTN + 4];

    float acc[8][4];
    #pragma unroll
    for (int i = 0; i < 8; ++i)
        #pragma unroll
        for (int j = 0; j < 4; ++j) acc[i][j] = 0.f;

    for (int k0 = 0; k0 < S; k0 += PTK) {
        // Stage P tile: 128 rows x 32 k = 1024 float4 -> 4 per thread.
        #pragma unroll
        for (int l = 0; l < 4; ++l) {
            int fl = tid + l * 256;
            int mm = fl >> 3;                  // 0..127 (probs row)
            int k4 = (fl & 7) * 4;             // 0..28
            float4 a = *(const float4*)(pbase + (size_t)mm * S + k0 + k4);
            As[k4 + 0][mm] = a.x; As[k4 + 1][mm] = a.y;
            As[k4 + 2][mm] = a.z; As[k4 + 3][mm] = a.w;
        }
        // Stage V tile: 32 rows x 64 = 512 float4 -> 2 per thread.
        #pragma unroll
        for (int l = 0; l < 2; ++l) {
            int fl = tid + l * 256;
            int kk = fl >> 4;                  // 0..31
            int n4 = (fl & 15) * 4;            // 0..60
            *(float4*)(&Bs[kk][n4]) =
                *(const float4*)(vbase + (size_t)(k0 + kk) * HD + n4);
        }
        __syncthreads();

        #pragma unroll
        for (int kk = 0; kk < PTK; ++kk) {
            float a[8], bb[4];
            *(float4*)(a)     = *(const float4*)(&As[kk][ty * 8]);
            *(float4*)(a + 4) = *(const float4*)(&As[kk][ty * 8 + 4]);
            *(float4*)(bb)    = *(const float4*)(&Bs[kk][tx * 4]);
            #pragma unroll
            for (int i = 0; i < 8; ++i)
                #pragma unroll
                for (int j = 0; j < 4; ++j)
                    acc[i][j] += a[i] * bb[j];
        }
        __syncthreads();
    }

    // Epilogue: out[b][s][h*64 + tx*4 ..], float4 stores.
    #pragma unroll
    for (int i = 0; i < 8; ++i) {
        int s = m0 + ty * 8 + i;
        float4 o;
        o.x = acc[i][0]; o.y = acc[i][1]; o.z = acc[i][2]; o.w = acc[i][3];
        *(float4*)(out + ((size_t)b * S + s) * D + h * HD + tx * 4) = o;
    }
}

// ---------------------------------------------------------------------------
extern "C" void kernel_launch(void* const* d_in, const int* in_sizes, int n_in,
                              void* d_out, int out_size, void* d_ws, size_t ws_size,
                              hipStream_t stream)
{
    const float* x  = (const float*)d_in[0];
    const float* Wq = (const float*)d_in[1];
    const float* bq = (const float*)d_in[2];
    const float* Wk = (const float*)d_in[3];
    const float* bk = (const float*)d_in[4];
    const float* Wv = (const float*)d_in[5];
    const float* bv = (const float*)d_in[6];

    float* out   = (float*)d_out;                         // [B,S,D] first
    float* probs = out + (size_t)B * S * D;               // then [B,H,S,S]
    float* ws    = (float*)d_ws;                          // q,k,v scratch
    (void)ws_size;  // needs 3*M*D*4 = 100,663,296 bytes

    dim3 g1(M / TM, D / TN, 3);
    qkv_proj_kernel<<<g1, 256, 0, stream>>>(x, Wq, bq, Wk, bk, Wv, bv, ws);

    const float* q = ws;
    const float* k = ws + (size_t)M * D;
    const float* v = ws + 2 * (size_t)M * D;

    dim3 g2(S / MQ, H, B);
    scores_softmax_kernel<<<g2, 256, 0, stream>>>(q, k, probs);

    dim3 g3(S / PTM, B * H);
    pv_kernel<<<g3, 256, 0, stream>>>(probs, v, out);
}